// Round 5
// baseline (397.797 us; speedup 1.0000x reference)
//
#include <hip/hip_runtime.h>
#include <math.h>

#define HD 256   // hidden dim (fixed per problem)

// ---------------- CSR build ----------------

__global__ void init_deg_kernel(int* __restrict__ deg, int* __restrict__ cursor, int n) {
    int i = blockIdx.x * blockDim.x + threadIdx.x;
    if (i < n) { deg[i] = 1; cursor[i] = 0; }   // 1 = self loop
}

__global__ void count_deg_kernel(const int* __restrict__ col, int E, int* __restrict__ deg) {
    int e = blockIdx.x * blockDim.x + threadIdx.x;
    if (e < E) atomicAdd(&deg[col[e]], 1);
}

// single-block exclusive scan over deg -> offs; also dinv[v] = rsqrt(deg[v])
__global__ __launch_bounds__(1024) void scan_kernel(const int* __restrict__ deg,
                                                    int* __restrict__ offs,
                                                    float* __restrict__ dinv, int n) {
    __shared__ int ps[1024];
    int tid = threadIdx.x;
    int chunk = (n + 1023) >> 10;
    int beg = tid * chunk;
    int end = min(beg + chunk, n);
    int s = 0;
    for (int i = beg; i < end; ++i) s += deg[i];
    ps[tid] = s;
    __syncthreads();
    for (int off = 1; off < 1024; off <<= 1) {
        int t = (tid >= off) ? ps[tid - off] : 0;
        __syncthreads();
        ps[tid] += t;
        __syncthreads();
    }
    int run = ps[tid] - s;  // exclusive prefix
    for (int i = beg; i < end; ++i) {
        offs[i] = run;
        run += deg[i];
        dinv[i] = rsqrtf((float)deg[i]);
    }
    if (tid == 1023) offs[n] = ps[1023];
}

__global__ void fill_csr_kernel(const int* __restrict__ ei, int E, int N,
                                const int* __restrict__ offs,
                                int* __restrict__ cursor, int* __restrict__ csr) {
    int idx = blockIdx.x * blockDim.x + threadIdx.x;
    int tot = E + N;
    if (idx >= tot) return;
    int r, c;
    if (idx < E) { r = ei[idx]; c = ei[E + idx]; }
    else         { r = c = idx - E; }                 // self loop
    int slot = atomicAdd(&cursor[c], 1);
    csr[offs[c] + slot] = r;
}

// ---------------- aggregation ----------------
// Inputs pre-scaled (h[u] = dinv[u]*act[u]) so the edge sum is a plain row sum.
// One WAVE per node, float4 lanes, neighbor loop unrolled x4.
// MODE 0: out[v] = dinv[v] * S
// MODE 1: out[v] = dinv[v] * relu(dinv[v]*S + bias)   (pre-scaled for next GEMM)

template<int MODE>
__global__ __launch_bounds__(256) void agg_kernel(const float* __restrict__ h,
                                                  const int* __restrict__ csr,
                                                  const int* __restrict__ offs,
                                                  const float* __restrict__ dinv,
                                                  const float* __restrict__ bias,
                                                  float* __restrict__ out, int N) {
    int gid  = blockIdx.x * blockDim.x + threadIdx.x;
    int v    = gid >> 6;
    int lane = gid & 63;
    if (v >= N) return;

    int beg = offs[v];
    int end = offs[v + 1];
    const float4* hp = (const float4*)h;   // row = 64 float4

    float4 acc = make_float4(0.f, 0.f, 0.f, 0.f);
    int i = beg;
    for (; i + 4 <= end; i += 4) {
        int u0 = csr[i], u1 = csr[i + 1], u2 = csr[i + 2], u3 = csr[i + 3];
        float4 r0 = hp[(size_t)u0 * 64 + lane];
        float4 r1 = hp[(size_t)u1 * 64 + lane];
        float4 r2 = hp[(size_t)u2 * 64 + lane];
        float4 r3 = hp[(size_t)u3 * 64 + lane];
        acc.x += (r0.x + r1.x) + (r2.x + r3.x);
        acc.y += (r0.y + r1.y) + (r2.y + r3.y);
        acc.z += (r0.z + r1.z) + (r2.z + r3.z);
        acc.w += (r0.w + r1.w) + (r2.w + r3.w);
    }
    for (; i < end; ++i) {
        int u = csr[i];
        float4 r = hp[(size_t)u * 64 + lane];
        acc.x += r.x; acc.y += r.y; acc.z += r.z; acc.w += r.w;
    }

    float dv = dinv[v];
    float4 o;
    if (MODE == 1) {
        float4 bv = ((const float4*)bias)[lane];
        o.x = dv * fmaxf(fmaf(dv, acc.x, bv.x), 0.f);
        o.y = dv * fmaxf(fmaf(dv, acc.y, bv.y), 0.f);
        o.z = dv * fmaxf(fmaf(dv, acc.z, bv.z), 0.f);
        o.w = dv * fmaxf(fmaf(dv, acc.w, bv.w), 0.f);
    } else {
        o.x = dv * acc.x; o.y = dv * acc.y; o.z = dv * acc.z; o.w = dv * acc.w;
    }
    ((float4*)out)[(size_t)v * 64 + lane] = o;
}

// ---------------- f32 GEMM: C[M,256] = A[M,256] @ W[256,256] ----------------
// BM=64, BN=128, BK=32, 128 threads (2 waves), 8x8 register tile (2.0 FLOP/B).
// Fragment cols = {4tx..+3} u {64+4tx..+3}; rows = {4ty..+3} u {32+4ty..+3}:
// every ds_read_b128 covers a CONTIGUOUS span -> no bank conflicts.
// HEADS: virtual N=512, per-block select of W2/W3, bias, out2/out3.
// SCALE_A: multiply A rows by scale[row] while staging (dinv fold for layer 1).

template<bool SCALE_A, bool HEADS>
__global__ __launch_bounds__(128) void gemm_kernel(const float* __restrict__ A,
                                                   const float* __restrict__ Wa,
                                                   const float* __restrict__ Wb,
                                                   const float* __restrict__ ba,
                                                   const float* __restrict__ bb,
                                                   const float* __restrict__ scale,
                                                   float* __restrict__ Ca,
                                                   float* __restrict__ Cb, int M) {
    constexpr int BM = 64, BN = 128, BK = 32;
    __shared__ float As[BK][BM];   // transposed A tile [k][m], 8 KB
    __shared__ float Ws[BK][BN];   // [k][n], 16 KB

    const int tid  = threadIdx.x;
    const int row0 = blockIdx.x * BM;
    int col0 = blockIdx.y * BN;

    const float* W    = Wa;
    const float* bias = ba;
    float*       C    = Ca;
    if (HEADS && col0 >= HD) { W = Wb; bias = bb; C = Cb; col0 -= HD; }

    const int tx = tid & 15;    // cols 4tx..+3 and 64+4tx..+3
    const int ty = tid >> 4;    // rows 4ty..+3 and 32+4ty..+3  (ty 0..7)

    // staging roles
    const int sa_m  = tid >> 1;          // A row within tile (0..63)
    const int sa_ks = (tid & 1) * 16;    // k-half (0 or 16)
    const int sw_kb = tid >> 5;          // W k sub-row (0..3)
    const int sw_c  = (tid & 31) * 4;    // W col chunk (0..124)

    const bool a_ok = (row0 + sa_m) < M;
    float a_scale = 1.f;
    if (SCALE_A && a_ok) a_scale = scale[row0 + sa_m];
    const float* Arow = A + (size_t)(row0 + sa_m) * HD + sa_ks;

    float acc[8][8];
#pragma unroll
    for (int i = 0; i < 8; ++i)
#pragma unroll
        for (int j = 0; j < 8; ++j) acc[i][j] = 0.f;

    for (int k0 = 0; k0 < HD; k0 += BK) {
        // ---- stage A (transposed) ----
        float4 av[4];
#pragma unroll
        for (int q = 0; q < 4; ++q) {
            av[q] = make_float4(0.f, 0.f, 0.f, 0.f);
            if (a_ok) {
                av[q] = *reinterpret_cast<const float4*>(&Arow[k0 + q * 4]);
                if (SCALE_A) { av[q].x *= a_scale; av[q].y *= a_scale; av[q].z *= a_scale; av[q].w *= a_scale; }
            }
        }
#pragma unroll
        for (int q = 0; q < 4; ++q) {
            As[sa_ks + q * 4 + 0][sa_m] = av[q].x;
            As[sa_ks + q * 4 + 1][sa_m] = av[q].y;
            As[sa_ks + q * 4 + 2][sa_m] = av[q].z;
            As[sa_ks + q * 4 + 3][sa_m] = av[q].w;
        }
        // ---- stage W ----
#pragma unroll
        for (int g = 0; g < 8; ++g) {
            int k = g * 4 + sw_kb;
            float4 wv = *reinterpret_cast<const float4*>(&W[(size_t)(k0 + k) * HD + col0 + sw_c]);
            *reinterpret_cast<float4*>(&Ws[k][sw_c]) = wv;
        }
        __syncthreads();

#pragma unroll 8
        for (int k = 0; k < BK; ++k) {
            float4 a0 = *reinterpret_cast<const float4*>(&As[k][ty * 4]);
            float4 a1 = *reinterpret_cast<const float4*>(&As[k][32 + ty * 4]);
            float4 b0 = *reinterpret_cast<const float4*>(&Ws[k][tx * 4]);
            float4 b1 = *reinterpret_cast<const float4*>(&Ws[k][64 + tx * 4]);
            float a_[8] = {a0.x, a0.y, a0.z, a0.w, a1.x, a1.y, a1.z, a1.w};
            float b_[8] = {b0.x, b0.y, b0.z, b0.w, b1.x, b1.y, b1.z, b1.w};
#pragma unroll
            for (int ii = 0; ii < 8; ++ii)
#pragma unroll
                for (int jj = 0; jj < 8; ++jj)
                    acc[ii][jj] = fmaf(a_[ii], b_[jj], acc[ii][jj]);
        }
        __syncthreads();
    }

    float badd[8];
#pragma unroll
    for (int j = 0; j < 8; ++j) {
        int c = (j < 4) ? (col0 + tx * 4 + j) : (col0 + 64 + tx * 4 + (j - 4));
        badd[j] = HEADS ? bias[c] : 0.f;
    }

#pragma unroll
    for (int i = 0; i < 8; ++i) {
        int row = row0 + ((i < 4) ? (ty * 4 + i) : (32 + ty * 4 + (i - 4)));
        if (row >= M) continue;
        float4 o0 = make_float4(acc[i][0] + badd[0], acc[i][1] + badd[1],
                                acc[i][2] + badd[2], acc[i][3] + badd[3]);
        float4 o1 = make_float4(acc[i][4] + badd[4], acc[i][5] + badd[5],
                                acc[i][6] + badd[6], acc[i][7] + badd[7]);
        *reinterpret_cast<float4*>(&C[(size_t)row * HD + col0 + tx * 4])      = o0;
        *reinterpret_cast<float4*>(&C[(size_t)row * HD + col0 + 64 + tx * 4]) = o1;
    }
}

// ---------------- launch ----------------

static inline size_t align_up(size_t x, size_t a) { return (x + a - 1) & ~(a - 1); }

extern "C" void kernel_launch(void* const* d_in, const int* in_sizes, int n_in,
                              void* d_out, int out_size, void* d_ws, size_t ws_size,
                              hipStream_t stream) {
    const int N = in_sizes[0] / HD;
    const int E = in_sizes[1] / 2;

    const float* x   = (const float*)d_in[0];
    const int*   ei  = (const int*)d_in[1];
    const float* W1  = (const float*)d_in[2];
    const float* W11 = (const float*)d_in[3];
    const float* W2  = (const float*)d_in[4];
    const float* W3  = (const float*)d_in[5];
    const float* b1  = (const float*)d_in[6];
    const float* b11 = (const float*)d_in[7];
    const float* b2  = (const float*)d_in[8];
    const float* b3  = (const float*)d_in[9];

    float* out2 = (float*)d_out;
    float* out3 = out2 + (size_t)N * HD;

    // workspace carve
    char* p = (char*)d_ws;
    int*   deg    = (int*)p;   p += align_up((size_t)N * 4, 256);
    int*   offs   = (int*)p;   p += align_up((size_t)(N + 1) * 4, 256);
    int*   cursor = (int*)p;   p += align_up((size_t)N * 4, 256);
    float* dinv   = (float*)p; p += align_up((size_t)N * 4, 256);
    int*   csr    = (int*)p;   p += align_up((size_t)(E + N) * 4, 256);
    float* bufA   = (float*)p; p += align_up((size_t)N * HD * 4, 256);
    float* bufB   = (float*)p; p += align_up((size_t)N * HD * 4, 256);
    (void)ws_size; (void)n_in; (void)out_size;

    // --- CSR of incoming edges (with self loops); dinv from scan ---
    init_deg_kernel<<<(N + 255) / 256, 256, 0, stream>>>(deg, cursor, N);
    count_deg_kernel<<<(E + 255) / 256, 256, 0, stream>>>(ei + E, E, deg);
    scan_kernel<<<1, 1024, 0, stream>>>(deg, offs, dinv, N);
    fill_csr_kernel<<<(E + N + 255) / 256, 256, 0, stream>>>(ei, E, N, offs, cursor, csr);

    const int gemm_gx = (N + 63) / 64;
    const int agg_blocks = (N + 3) / 4;   // 4 waves (nodes) per 256-thread block

    // layer 1: z1 = (dinv .* x) @ W1 ; t1 = dinv*relu(dinv*sum + b1)
    gemm_kernel<true, false><<<dim3(gemm_gx, HD / 128), 128, 0, stream>>>(
        x, W1, nullptr, nullptr, nullptr, dinv, bufA, nullptr, N);
    agg_kernel<1><<<agg_blocks, 256, 0, stream>>>(bufA, csr, offs, dinv, b1, bufB, N);

    // layer 2: z2 = t1 @ W1_1 ; t2 = dinv*relu(dinv*sum + b1_1)
    gemm_kernel<false, false><<<dim3(gemm_gx, HD / 128), 128, 0, stream>>>(
        bufB, W11, nullptr, nullptr, nullptr, nullptr, bufA, nullptr, N);
    agg_kernel<1><<<agg_blocks, 256, 0, stream>>>(bufA, csr, offs, dinv, b11, bufB, N);

    // shared agg: g = dinv * sum(t2)
    agg_kernel<0><<<agg_blocks, 256, 0, stream>>>(bufB, csr, offs, dinv, nullptr, bufA, N);

    // fused heads: out2 = g@W2+b2 ; out3 = g@W3+b3  (virtual N=512)
    gemm_kernel<false, true><<<dim3(gemm_gx, 2 * HD / 128), 128, 0, stream>>>(
        bufA, W2, W3, b2, b3, nullptr, out2, out3, N);
}

// Round 6
// 319.979 us; speedup vs baseline: 1.2432x; 1.2432x over previous
//
#include <hip/hip_runtime.h>
#include <math.h>

#define HD 256   // hidden dim (fixed per problem)

typedef short bf16x8 __attribute__((ext_vector_type(8)));
typedef float f32x4  __attribute__((ext_vector_type(4)));

__device__ __forceinline__ unsigned short f2bf(float f) {   // RNE f32->bf16
    unsigned u = __builtin_bit_cast(unsigned, f);
    unsigned r = (u + 0x7fffu + ((u >> 16) & 1u)) >> 16;
    return (unsigned short)r;
}
__device__ __forceinline__ float bf2f(unsigned b) {
    return __builtin_bit_cast(float, (b & 0xffffu) << 16);
}

// ---------------- CSR build ----------------

__global__ void init_deg_kernel(int* __restrict__ deg, int* __restrict__ cursor, int n) {
    int i = blockIdx.x * blockDim.x + threadIdx.x;
    if (i < n) { deg[i] = 1; cursor[i] = 0; }   // 1 = self loop
}

__global__ void count_deg_kernel(const int* __restrict__ col, int E, int* __restrict__ deg) {
    int e = blockIdx.x * blockDim.x + threadIdx.x;
    if (e < E) atomicAdd(&deg[col[e]], 1);
}

__global__ __launch_bounds__(1024) void scan_kernel(const int* __restrict__ deg,
                                                    int* __restrict__ offs,
                                                    float* __restrict__ dinv, int n) {
    __shared__ int ps[1024];
    int tid = threadIdx.x;
    int chunk = (n + 1023) >> 10;
    int beg = tid * chunk;
    int end = min(beg + chunk, n);
    int s = 0;
    for (int i = beg; i < end; ++i) s += deg[i];
    ps[tid] = s;
    __syncthreads();
    for (int off = 1; off < 1024; off <<= 1) {
        int t = (tid >= off) ? ps[tid - off] : 0;
        __syncthreads();
        ps[tid] += t;
        __syncthreads();
    }
    int run = ps[tid] - s;  // exclusive prefix
    for (int i = beg; i < end; ++i) {
        offs[i] = run;
        run += deg[i];
        dinv[i] = rsqrtf((float)deg[i]);
    }
    if (tid == 1023) offs[n] = ps[1023];
}

__global__ void fill_csr_kernel(const int* __restrict__ ei, int E, int N,
                                const int* __restrict__ offs,
                                int* __restrict__ cursor, int* __restrict__ csr) {
    int idx = blockIdx.x * blockDim.x + threadIdx.x;
    int tot = E + N;
    if (idx >= tot) return;
    int r, c;
    if (idx < E) { r = ei[idx]; c = ei[E + idx]; }
    else         { r = c = idx - E; }                 // self loop
    int slot = atomicAdd(&cursor[c], 1);
    csr[offs[c] + slot] = r;
}

// ---------------- W pre-pack: f32 W[256][256] -> MFMA-fragment-linear bf16 hi/lo ----------------
// Frag (nc,kc): 16x16x32 B-operand tile, cols nc*16..+15, k kc*32..+31.
// Slot rule (same as A side, so any intra-frag k permutation cancels):
//   lane l, elem e  <->  W[kc*32 + 8*(l>>4) + e][nc*16 + (l&15)]
// Layout: pk[mat][nc][kc][lane][e], 65536 elems per matrix.

__global__ __launch_bounds__(256) void packW_kernel(const float* __restrict__ W0,
                                                    const float* __restrict__ W1,
                                                    const float* __restrict__ W2,
                                                    const float* __restrict__ W3,
                                                    unsigned short* __restrict__ pkhi,
                                                    unsigned short* __restrict__ pklo) {
    int gid = blockIdx.x * 256 + threadIdx.x;   // 32768 threads total
    int mat  = gid >> 13;
    int rem  = gid & 8191;
    int nc   = rem >> 9;
    int kc   = (rem >> 6) & 7;
    int lane = rem & 63;
    const float* W = (mat == 0) ? W0 : (mat == 1) ? W1 : (mat == 2) ? W2 : W3;
    int col = nc * 16 + (lane & 15);
    int kb  = kc * 32 + (lane >> 4) * 8;
    alignas(16) unsigned short h[8], l[8];
#pragma unroll
    for (int e = 0; e < 8; ++e) {
        float w = W[(size_t)(kb + e) * HD + col];
        unsigned short hb = f2bf(w);
        h[e] = hb;
        l[e] = f2bf(w - bf2f(hb));
    }
    size_t off = (size_t)mat * 65536 + ((size_t)(nc * 8 + kc) * 64 + lane) * 8;
    *(uint4*)&pkhi[off] = *(const uint4*)h;
    *(uint4*)&pklo[off] = *(const uint4*)l;
}

// ---------------- x conversion: thi/tlo = split(dinv[row] * x[row][:]) ----------------

__global__ __launch_bounds__(256) void convx_kernel(const float* __restrict__ x,
                                                    const float* __restrict__ dinv,
                                                    unsigned short* __restrict__ thi,
                                                    unsigned short* __restrict__ tlo, int N) {
    int gid = blockIdx.x * 256 + threadIdx.x;   // N*32, 8 elems each
    if (gid >= N * 32) return;
    int row = gid >> 5;
    int c8  = (gid & 31) * 8;
    float s = dinv[row];
    const float4* xp = (const float4*)(x + (size_t)row * HD + c8);
    float4 v0 = xp[0], v1 = xp[1];
    float vals[8] = {v0.x, v0.y, v0.z, v0.w, v1.x, v1.y, v1.z, v1.w};
    alignas(16) unsigned short h[8], l[8];
#pragma unroll
    for (int e = 0; e < 8; ++e) {
        float t = vals[e] * s;
        unsigned short hb = f2bf(t);
        h[e] = hb;
        l[e] = f2bf(t - bf2f(hb));
    }
    size_t off = (size_t)row * HD + c8;
    *(uint4*)&thi[off] = *(const uint4*)h;
    *(uint4*)&tlo[off] = *(const uint4*)l;
}

// ---------------- aggregation (hidden layers) ----------------
// read f32 z, gather row-sum, t = dinv*relu(dinv*S + b), write split bf16 hi/lo.
// One wave per node, float4 lanes, unroll x4.

__global__ __launch_bounds__(256) void agg_relu_split_kernel(const float* __restrict__ z,
                                                             const int* __restrict__ csr,
                                                             const int* __restrict__ offs,
                                                             const float* __restrict__ dinv,
                                                             const float* __restrict__ bias,
                                                             unsigned short* __restrict__ thi,
                                                             unsigned short* __restrict__ tlo, int N) {
    int gid  = blockIdx.x * blockDim.x + threadIdx.x;
    int v    = gid >> 6;
    int lane = gid & 63;
    if (v >= N) return;

    int beg = offs[v];
    int end = offs[v + 1];
    const float4* hp = (const float4*)z;

    float4 acc = make_float4(0.f, 0.f, 0.f, 0.f);
    int i = beg;
    for (; i + 4 <= end; i += 4) {
        int u0 = csr[i], u1 = csr[i + 1], u2 = csr[i + 2], u3 = csr[i + 3];
        float4 r0 = hp[(size_t)u0 * 64 + lane];
        float4 r1 = hp[(size_t)u1 * 64 + lane];
        float4 r2 = hp[(size_t)u2 * 64 + lane];
        float4 r3 = hp[(size_t)u3 * 64 + lane];
        acc.x += (r0.x + r1.x) + (r2.x + r3.x);
        acc.y += (r0.y + r1.y) + (r2.y + r3.y);
        acc.z += (r0.z + r1.z) + (r2.z + r3.z);
        acc.w += (r0.w + r1.w) + (r2.w + r3.w);
    }
    for (; i < end; ++i) {
        int u = csr[i];
        float4 r = hp[(size_t)u * 64 + lane];
        acc.x += r.x; acc.y += r.y; acc.z += r.z; acc.w += r.w;
    }

    float dv = dinv[v];
    float4 bv = ((const float4*)bias)[lane];
    float t[4];
    t[0] = dv * fmaxf(fmaf(dv, acc.x, bv.x), 0.f);
    t[1] = dv * fmaxf(fmaf(dv, acc.y, bv.y), 0.f);
    t[2] = dv * fmaxf(fmaf(dv, acc.z, bv.z), 0.f);
    t[3] = dv * fmaxf(fmaf(dv, acc.w, bv.w), 0.f);
    alignas(8) unsigned short h[4], l[4];
#pragma unroll
    for (int e = 0; e < 4; ++e) {
        unsigned short hb = f2bf(t[e]);
        h[e] = hb;
        l[e] = f2bf(t[e] - bf2f(hb));
    }
    size_t off = (size_t)v * HD + lane * 4;
    *(uint2*)&thi[off] = *(const uint2*)h;
    *(uint2*)&tlo[off] = *(const uint2*)l;
}

// ---------------- shared aggregation: g = dinv * sum(t2) ----------------
// reads bf16 hi/lo pairs (hi+lo ~= f32), writes split bf16 hi/lo.

__global__ __launch_bounds__(256) void agg_pair_kernel(const unsigned short* __restrict__ thi,
                                                       const unsigned short* __restrict__ tlo,
                                                       const int* __restrict__ csr,
                                                       const int* __restrict__ offs,
                                                       const float* __restrict__ dinv,
                                                       unsigned short* __restrict__ ghi,
                                                       unsigned short* __restrict__ glo, int N) {
    int gid  = blockIdx.x * blockDim.x + threadIdx.x;
    int v    = gid >> 6;
    int lane = gid & 63;
    if (v >= N) return;

    int beg = offs[v];
    int end = offs[v + 1];
    const uint2* hp = (const uint2*)thi;   // row = 64 uint2 (4 bf16 each)
    const uint2* lp = (const uint2*)tlo;

    float a0 = 0.f, a1 = 0.f, a2 = 0.f, a3 = 0.f;
    int i = beg;
    for (; i + 2 <= end; i += 2) {
        int u0 = csr[i], u1 = csr[i + 1];
        uint2 h0 = hp[(size_t)u0 * 64 + lane];
        uint2 l0 = lp[(size_t)u0 * 64 + lane];
        uint2 h1 = hp[(size_t)u1 * 64 + lane];
        uint2 l1 = lp[(size_t)u1 * 64 + lane];
        a0 += (bf2f(h0.x) + bf2f(l0.x)) + (bf2f(h1.x) + bf2f(l1.x));
        a1 += (bf2f(h0.x >> 16) + bf2f(l0.x >> 16)) + (bf2f(h1.x >> 16) + bf2f(l1.x >> 16));
        a2 += (bf2f(h0.y) + bf2f(l0.y)) + (bf2f(h1.y) + bf2f(l1.y));
        a3 += (bf2f(h0.y >> 16) + bf2f(l0.y >> 16)) + (bf2f(h1.y >> 16) + bf2f(l1.y >> 16));
    }
    for (; i < end; ++i) {
        int u = csr[i];
        uint2 h0 = hp[(size_t)u * 64 + lane];
        uint2 l0 = lp[(size_t)u * 64 + lane];
        a0 += bf2f(h0.x) + bf2f(l0.x);
        a1 += bf2f(h0.x >> 16) + bf2f(l0.x >> 16);
        a2 += bf2f(h0.y) + bf2f(l0.y);
        a3 += bf2f(h0.y >> 16) + bf2f(l0.y >> 16);
    }

    float dv = dinv[v];
    float t[4] = {dv * a0, dv * a1, dv * a2, dv * a3};
    alignas(8) unsigned short h[4], l[4];
#pragma unroll
    for (int e = 0; e < 4; ++e) {
        unsigned short hb = f2bf(t[e]);
        h[e] = hb;
        l[e] = f2bf(t[e] - bf2f(hb));
    }
    size_t off = (size_t)v * HD + lane * 4;
    *(uint2*)&ghi[off] = *(const uint2*)h;
    *(uint2*)&glo[off] = *(const uint2*)l;
}

// ---------------- MFMA GEMM: C[M,256] = (Ahi+Alo) @ (Whi+Wlo), 3-term split ----------------
// No LDS, no barriers: W is L2-resident pre-packed frags; A row-major bf16 loads frag-direct.
// Wave tile 16 rows x 64 cols (4 nf frags, acc 16 VGPR) -> 5000 waves (~19.6/CU) hidden.
// Block 256 thr = 4 waves stacked by row (64 rows). grid = (ceil(M/64), 4 or 8).
// mfma_f32_16x16x32_bf16: D col=lane&15, row=(lane>>4)*4+reg  [m89-verified].
// A slot: lane holds A[row0+(lane&15)][kc*32 + 8*(lane>>4) + e] -- same slot rule as packW,
// so any intra-frag k permutation cancels between operands.

template<bool HEADS>
__global__ __launch_bounds__(256) void gemm_mfma_kernel(const unsigned short* __restrict__ Ahi,
                                                        const unsigned short* __restrict__ Alo,
                                                        const unsigned short* __restrict__ pkhi,
                                                        const unsigned short* __restrict__ pklo,
                                                        const float* __restrict__ ba,
                                                        const float* __restrict__ bb,
                                                        float* __restrict__ Ca,
                                                        float* __restrict__ Cb, int M) {
    const int tid  = threadIdx.x;
    const int lane = tid & 63;
    const int wave = tid >> 6;
    const int by   = blockIdx.y;

    const int sel = HEADS ? (by >> 2) : 0;            // heads: 0->W2/out2, 1->W3/out3
    const int nc0 = HEADS ? ((by & 3) * 4) : (by * 4);
    const unsigned short* ph = pkhi + (size_t)sel * 65536;
    const unsigned short* pl = pklo + (size_t)sel * 65536;
    float*       C    = sel ? Cb : Ca;
    const float* bias = sel ? bb : ba;

    const int row0 = blockIdx.x * 64 + wave * 16;
    const int rowA = min(row0 + (lane & 15), M - 1);  // clamp: garbage only feeds unstored rows
    const int kg   = lane >> 4;

    const unsigned short* aH = Ahi + (size_t)rowA * HD + kg * 8;
    const unsigned short* aL = Alo + (size_t)rowA * HD + kg * 8;
    const size_t wbase = ((size_t)(nc0 * 8) * 64 + lane) * 8;

    f32x4 acc[4];
#pragma unroll
    for (int nf = 0; nf < 4; ++nf) acc[nf] = (f32x4)0.f;

#pragma unroll 2
    for (int kc = 0; kc < 8; ++kc) {
        bf16x8 ah = *(const bf16x8*)(aH + kc * 32);
        bf16x8 al = *(const bf16x8*)(aL + kc * 32);
        size_t wb = wbase + (size_t)kc * 512;         // kc stride = 64*8
        bf16x8 wh[4], wl[4];
#pragma unroll
        for (int nf = 0; nf < 4; ++nf) {
            wh[nf] = *(const bf16x8*)(ph + wb + (size_t)nf * 4096);  // nf stride = 8*64*8
            wl[nf] = *(const bf16x8*)(pl + wb + (size_t)nf * 4096);
        }
#pragma unroll
        for (int nf = 0; nf < 4; ++nf) {
            acc[nf] = __builtin_amdgcn_mfma_f32_16x16x32_bf16(ah, wh[nf], acc[nf], 0, 0, 0);
            acc[nf] = __builtin_amdgcn_mfma_f32_16x16x32_bf16(ah, wl[nf], acc[nf], 0, 0, 0);
            acc[nf] = __builtin_amdgcn_mfma_f32_16x16x32_bf16(al, wh[nf], acc[nf], 0, 0, 0);
        }
    }

#pragma unroll
    for (int nf = 0; nf < 4; ++nf) {
        int col = (nc0 + nf) * 16 + (lane & 15);
        float badd = HEADS ? bias[col] : 0.f;
#pragma unroll
        for (int r = 0; r < 4; ++r) {
            int row = row0 + kg * 4 + r;
            if (row < M) C[(size_t)row * HD + col] = acc[nf][r] + badd;
        }
    }
}

// ---------------- launch ----------------

static inline size_t align_up(size_t x, size_t a) { return (x + a - 1) & ~(a - 1); }

extern "C" void kernel_launch(void* const* d_in, const int* in_sizes, int n_in,
                              void* d_out, int out_size, void* d_ws, size_t ws_size,
                              hipStream_t stream) {
    const int N = in_sizes[0] / HD;
    const int E = in_sizes[1] / 2;

    const float* x   = (const float*)d_in[0];
    const int*   ei  = (const int*)d_in[1];
    const float* W1  = (const float*)d_in[2];
    const float* W11 = (const float*)d_in[3];
    const float* W2  = (const float*)d_in[4];
    const float* W3  = (const float*)d_in[5];
    const float* b1  = (const float*)d_in[6];
    const float* b11 = (const float*)d_in[7];
    const float* b2  = (const float*)d_in[8];
    const float* b3  = (const float*)d_in[9];

    float* out2 = (float*)d_out;
    float* out3 = out2 + (size_t)N * HD;

    // workspace carve (~44 MB)
    char* p = (char*)d_ws;
    int*   deg    = (int*)p;   p += align_up((size_t)N * 4, 256);
    int*   offs   = (int*)p;   p += align_up((size_t)(N + 1) * 4, 256);
    int*   cursor = (int*)p;   p += align_up((size_t)N * 4, 256);
    float* dinv   = (float*)p; p += align_up((size_t)N * 4, 256);
    int*   csr    = (int*)p;   p += align_up((size_t)(E + N) * 4, 256);
    unsigned short* pkhi = (unsigned short*)p; p += align_up((size_t)4 * 65536 * 2, 256);
    unsigned short* pklo = (unsigned short*)p; p += align_up((size_t)4 * 65536 * 2, 256);
    float* bufZ = (float*)p;   p += align_up((size_t)N * HD * 4, 256);
    unsigned short* bufThi = (unsigned short*)p; p += align_up((size_t)N * HD * 2, 256);
    unsigned short* bufTlo = (unsigned short*)p; p += align_up((size_t)N * HD * 2, 256);
    // g reuses bufZ (z2 dead by then): 2 x 10.24MB fits in 20.48MB
    unsigned short* bufGhi = (unsigned short*)bufZ;
    unsigned short* bufGlo = bufGhi + (size_t)N * HD;
    (void)ws_size; (void)n_in; (void)out_size;

    // --- CSR of incoming edges (with self loops); dinv from scan ---
    init_deg_kernel<<<(N + 255) / 256, 256, 0, stream>>>(deg, cursor, N);
    count_deg_kernel<<<(E + 255) / 256, 256, 0, stream>>>(ei + E, E, deg);
    scan_kernel<<<1, 1024, 0, stream>>>(deg, offs, dinv, N);
    fill_csr_kernel<<<(E + N + 255) / 256, 256, 0, stream>>>(ei, E, N, offs, cursor, csr);

    // --- pre-pack weights, convert x ---
    packW_kernel<<<128, 256, 0, stream>>>(W1, W11, W2, W3, pkhi, pklo);
    convx_kernel<<<(N * 32 + 255) / 256, 256, 0, stream>>>(x, dinv, bufThi, bufTlo, N);

    const int gx = (N + 63) / 64;
    const int agg_blocks = (N + 3) / 4;

    // layer 1: z1 = Xs @ W1 ; t1 = split(dinv*relu(dinv*sum + b1))
    gemm_mfma_kernel<false><<<dim3(gx, 4), 256, 0, stream>>>(
        bufThi, bufTlo, pkhi + 0 * 65536, pklo + 0 * 65536, nullptr, nullptr, bufZ, nullptr, N);
    agg_relu_split_kernel<<<agg_blocks, 256, 0, stream>>>(bufZ, csr, offs, dinv, b1, bufThi, bufTlo, N);

    // layer 2: z2 = t1 @ W1_1 ; t2 = split(dinv*relu(dinv*sum + b1_1))
    gemm_mfma_kernel<false><<<dim3(gx, 4), 256, 0, stream>>>(
        bufThi, bufTlo, pkhi + 1 * 65536, pklo + 1 * 65536, nullptr, nullptr, bufZ, nullptr, N);
    agg_relu_split_kernel<<<agg_blocks, 256, 0, stream>>>(bufZ, csr, offs, dinv, b11, bufThi, bufTlo, N);

    // shared agg: g = split(dinv * sum(t2))
    agg_pair_kernel<<<agg_blocks, 256, 0, stream>>>(bufThi, bufTlo, csr, offs, dinv, bufGhi, bufGlo, N);

    // fused heads: out2 = g@W2+b2 ; out3 = g@W3+b3
    gemm_mfma_kernel<true><<<dim3(gx, 8), 256, 0, stream>>>(
        bufGhi, bufGlo, pkhi + 2 * 65536, pklo + 2 * 65536, b2, b3, out2, out3, N);
}